// Round 15
// baseline (78.604 us; speedup 1.0000x reference)
//
#include <hip/hip_runtime.h>

#define DIM 512
#define HIDDEN 1024
#define H2 2048        // 2*HIDDEN
#define NEXP 32
#define TOPK 4
#define TOKENS 64
#define NPAIR (TOKENS*TOPK)   // 256
#define PADK 8                // ushort pad per LDS row (2-way bank alias = free)

typedef __attribute__((ext_vector_type(8))) short short8;
typedef __attribute__((ext_vector_type(4))) float fp32x4;
typedef __attribute__((ext_vector_type(4))) unsigned short ushort4v;

// f32 -> bf16 round-nearest-even
__device__ __forceinline__ unsigned short f2bf_rne(float f) {
    unsigned u = __float_as_uint(f);
    return (unsigned short)((u + 0x7FFFu + ((u >> 16) & 1u)) >> 16);
}
__device__ __forceinline__ float dot4f(float4 a, float4 b) {
    return a.x*b.x + a.y*b.y + a.z*b.z + a.w*b.w;
}
// paired split: hi-pack = bf16_trunc(a) | bf16_trunc(b)<<16 (v_perm-able),
// lo-pack = bf16_trunc(a - hi_a) | bf16_trunc(b - hi_b)<<16.
// hi+lo error <= 2^-16 |a| (vs 2^-17 with RNE lo) - negligible.
__device__ __forceinline__ void split_pack2(float a, float b,
                                            unsigned& hi, unsigned& lo) {
    unsigned ua = __float_as_uint(a), ub = __float_as_uint(b);
    float ra = a - __uint_as_float(ua & 0xFFFF0000u);
    float rb = b - __uint_as_float(ub & 0xFFFF0000u);
    hi = (ua >> 16) | (ub & 0xFFFF0000u);
    lo = (__float_as_uint(ra) >> 16) | (__float_as_uint(rb) & 0xFFFF0000u);
}

// split ca,cb float4 -> A-frags (hi, lo) and run 2 MFMAs against LDS B-frag
#define MFMA_STEP(xbuf, ca, cb, kt) do {                                      \
    union { short8 s; unsigned u[4]; } ah_, al_;                              \
    split_pack2((ca).x, (ca).y, ah_.u[0], al_.u[0]);                          \
    split_pack2((ca).z, (ca).w, ah_.u[1], al_.u[1]);                          \
    split_pack2((cb).x, (cb).y, ah_.u[2], al_.u[2]);                          \
    split_pack2((cb).z, (cb).w, ah_.u[3], al_.u[3]);                          \
    short8 bh = *(const short8*)&xbuf[lr][(kt)*32 + lg*8];                    \
    acc = __builtin_amdgcn_mfma_f32_16x16x32_bf16(ah_.s, bh, acc, 0, 0, 0);   \
    acc = __builtin_amdgcn_mfma_f32_16x16x32_bf16(al_.s, bh, acc, 0, 0, 0);   \
} while (0)

// ---------------- router: 16-way split-K logits + top4 + softmax ----------
// 64 blocks x 512 thr. Also zeroes out[b][:] for the fused atomic combine.
__global__ __launch_bounds__(512) void router_kernel(
        const float* __restrict__ x, const float* __restrict__ Wg,
        const float* __restrict__ bg, int* __restrict__ idxw,
        float* __restrict__ eww, float* __restrict__ out) {
    int b = blockIdx.x;
    int tid = threadIdx.x;
    int e = tid >> 4, s = tid & 15;
    __shared__ float xs[DIM];
    __shared__ float g[NEXP];
    if (tid < DIM/4) {
        *(float4*)&xs[4*tid] = *(const float4*)(x + (size_t)b*DIM + 4*tid);
    }
    if (tid >= 128 && tid < 256) {
        int i = tid - 128;
        *(float4*)(out + (size_t)b*DIM + 4*i) = make_float4(0.f,0.f,0.f,0.f);
    }
    __syncthreads();
    const float* wr = Wg + e*DIM;
    float acc = 0.f;
    #pragma unroll
    for (int i = 0; i < 8; ++i) {
        int d4 = s + 16*i;
        float4 wv = *(const float4*)(wr + 4*d4);
        float4 xv = *(const float4*)&xs[4*d4];
        acc += dot4f(wv, xv);
    }
    #pragma unroll
    for (int m = 1; m < 16; m <<= 1) acc += __shfl_xor(acc, m);
    if (s == 0) g[e] = acc + bg[e];
    __syncthreads();
    if (tid == 0) {
        int sel[TOPK]; float val[TOPK];
        bool used[NEXP];
        for (int i = 0; i < NEXP; ++i) used[i] = false;
        for (int k = 0; k < TOPK; ++k) {
            float best = -1e30f; int bi = 0;
            for (int ee = 0; ee < NEXP; ++ee) {
                if (!used[ee] && g[ee] > best) { best = g[ee]; bi = ee; }
            }
            used[bi] = true; sel[k] = bi; val[k] = best;
        }
        float m = val[0];
        float p[TOPK]; float sum = 0.f;
        for (int k = 0; k < TOPK; ++k) { p[k] = __expf(val[k] - m); sum += p[k]; }
        float inv = 1.f / sum;
        for (int k = 0; k < TOPK; ++k) {
            idxw[b*TOPK + k] = sel[k];
            eww[b*TOPK + k]  = p[k] * inv;
        }
    }
}

// Ballot-based deterministic per-expert list build. Caller: 256 threads.
__device__ __forceinline__ int build_list_ballot(
        const int* __restrict__ idxw, int e, int tid,
        int* slist, unsigned long long* smask, int* scnt) {
    int me = idxw[tid];
    unsigned long long m = __ballot(me == e);
    int l = tid & 63, w = tid >> 6;
    if (l == 0) smask[w] = m;
    __syncthreads();
    if (me == e) {
        int r = __popcll(m & ((1ull << l) - 1ull));
        #pragma unroll
        for (int q = 0; q < 4; ++q) r += (q < w) ? __popcll(smask[q]) : 0;
        slist[r] = tid;
    }
    if (tid == 0) {
        *scnt = __popcll(smask[0]) + __popcll(smask[1])
              + __popcll(smask[2]) + __popcll(smask[3]);
    }
    __syncthreads();
    return *scnt;
}

// ---------------- expert up-proj + swiglu (MFMA, depth-2 branchless) ------
// block = 256 thr = 4 waves; wave owns 16 raw w1 rows x 16 tokens.
// grid (NEXP, H2/64 = 32). 2 MFMAs per K-tile: wh*xh + wl*xh.
__global__ __launch_bounds__(256, 4) void expert_up(
        const float* __restrict__ x, const float* __restrict__ w1,
        const float* __restrict__ b1, const int* __restrict__ idxw,
        float* __restrict__ act) {
    int e = blockIdx.x;
    int tid = threadIdx.x;
    __shared__ int slist[TOKENS];
    __shared__ unsigned long long smask[4];
    __shared__ int scnt;
    int n = build_list_ballot(idxw, e, tid, slist, smask, &scnt);
    if (n == 0) return;
    int wv = tid >> 6, l = tid & 63;
    int lr = l & 15, lg = l >> 4;          // A row-in-tile / k-group
    __shared__ unsigned short xh[16][DIM + PADK];   // 16.25 KB
    int r0 = blockIdx.y * 64 + wv * 16;    // raw row tile base (0..2047)
    const float4* w4 = (const float4*)(w1 + ((size_t)e*H2 + r0 + lr) * DIM + lg * 8);

    for (int t0 = 0; t0 < n; t0 += 16) {
        int nn = min(16, n - t0);
        __syncthreads();
        for (int i = tid; i < 16 * (DIM/4); i += 256) {
            int j = i >> 7, dd = i & 127;             // DIM/4 = 128
            float4 v = make_float4(0.f, 0.f, 0.f, 0.f);
            if (j < nn) {
                int p = slist[t0 + j];
                v = *(const float4*)(x + (size_t)(p >> 2)*DIM + 4*dd);
            }
            ushort4v hv;
            hv[0] = f2bf_rne(v.x); hv[1] = f2bf_rne(v.y);
            hv[2] = f2bf_rne(v.z); hv[3] = f2bf_rne(v.w);
            *(ushort4v*)&xh[j][4*dd] = hv;
        }
        __syncthreads();

        fp32x4 acc = {0.f, 0.f, 0.f, 0.f};
        float4 c0 = w4[0], c1 = w4[1];      // kt=0 in flight
        for (int kt = 0; kt < 16; ++kt) {
            int ktn = (kt + 1) & 15;        // branchless wrap (last reloads kt0)
            float4 n0 = w4[8*ktn], n1 = w4[8*ktn + 1];
            MFMA_STEP(xh, c0, c1, kt);
            c0 = n0; c1 = n1;
        }

        // D: col = l&15 = token, row = (l>>4)*4 + reg.
        int tok = lr;
        if (tok < nn) {
            int p = slist[t0 + tok];
            #pragma unroll
            for (int u = 0; u < 2; ++u) {
                int rr = r0 + lg*4 + 2*u;             // even raw row
                float h0 = acc[2*u]   + b1[e*H2 + rr];
                float h1 = acc[2*u+1] + b1[e*H2 + rr + 1];
                float gv = fminf(h0, 7.f);
                float lvv = fminf(fmaxf(h1, -7.f), 7.f);
                float sg = 1.f / (1.f + __expf(-1.702f * gv));
                act[(size_t)p*HIDDEN + (rr >> 1)] = gv * sg * (lvv + 1.f);
            }
        }
    }
}

// ---------------- expert down-proj + fused combine (k-split x2, atomic) ---
// block = 256 thr = 4 waves; wave owns 16 w2 rows x 16 tokens x K/2.
// grid (NEXP, DIM/64 = 8, 2). out pre-zeroed by router; kz 0 carries bias.
__global__ __launch_bounds__(256, 4) void expert_down(
        const float* __restrict__ act, const float* __restrict__ w2,
        const float* __restrict__ b2, const int* __restrict__ idxw,
        const float* __restrict__ eww, float* __restrict__ out) {
    int e = blockIdx.x;
    int kz = blockIdx.z;                   // K half: 0 or 1
    int tid = threadIdx.x;
    __shared__ int slist[TOKENS];
    __shared__ unsigned long long smask[4];
    __shared__ int scnt;
    int n = build_list_ballot(idxw, e, tid, slist, smask, &scnt);
    if (n == 0) return;
    int wv = tid >> 6, l = tid & 63;
    int lr = l & 15, lg = l >> 4;
    __shared__ unsigned short as_[16][HIDDEN/2 + PADK];  // 16.25 KB
    int r0 = blockIdx.y * 64 + wv * 16;    // output row tile base (0..511)
    const float4* w4 = (const float4*)(w2 + ((size_t)e*DIM + r0 + lr) * HIDDEN
                                       + kz * (HIDDEN/2) + lg * 8);

    for (int t0 = 0; t0 < n; t0 += 16) {
        int nn = min(16, n - t0);
        __syncthreads();
        for (int i = tid; i < 16 * (HIDDEN/8); i += 256) {   // this half only
            int j = i >> 7, dd = i & 127;                    // 128 f4 per row-half
            float4 v = make_float4(0.f, 0.f, 0.f, 0.f);
            if (j < nn) {
                int p = slist[t0 + j];
                v = *(const float4*)(act + (size_t)p*HIDDEN + kz*(HIDDEN/2) + 4*dd);
            }
            ushort4v hv;
            hv[0] = f2bf_rne(v.x); hv[1] = f2bf_rne(v.y);
            hv[2] = f2bf_rne(v.z); hv[3] = f2bf_rne(v.w);
            *(ushort4v*)&as_[j][4*dd] = hv;
        }
        __syncthreads();

        fp32x4 acc = {0.f, 0.f, 0.f, 0.f};
        float4 c0 = w4[0], c1 = w4[1];
        for (int kt = 0; kt < 16; ++kt) {
            int ktn = (kt + 1) & 15;        // branchless wrap
            float4 n0 = w4[8*ktn], n1 = w4[8*ktn + 1];
            MFMA_STEP(as_, c0, c1, kt);
            c0 = n0; c1 = n1;
        }

        int tok = lr;
        if (tok < nn) {
            int p = slist[t0 + tok];
            float ew = eww[p];
            int b = p >> 2;
            #pragma unroll
            for (int u = 0; u < 4; ++u) {
                int rr = r0 + lg*4 + u;
                float v = acc[u] + (kz == 0 ? b2[e*DIM + rr] : 0.f);
                atomicAdd(out + (size_t)b*DIM + rr, ew * v);
            }
        }
    }
}

extern "C" void kernel_launch(void* const* d_in, const int* in_sizes, int n_in,
                              void* d_out, int out_size, void* d_ws, size_t ws_size,
                              hipStream_t stream) {
    const float* x  = (const float*)d_in[0];
    const float* Wg = (const float*)d_in[1];
    const float* bg = (const float*)d_in[2];
    const float* w1 = (const float*)d_in[3];
    const float* b1 = (const float*)d_in[4];
    const float* w2 = (const float*)d_in[5];
    const float* b2 = (const float*)d_in[6];
    float* out = (float*)d_out;

    char* ws = (char*)d_ws;
    int*   idxw = (int*)(ws);                   // 256 ints
    float* eww  = (float*)(ws + 1024);          // 256 floats
    float* act  = (float*)(ws + 16384);         // 256*1024 f32 = 1 MB

    router_kernel<<<TOKENS, 512, 0, stream>>>(x, Wg, bg, idxw, eww, out);
    expert_up<<<dim3(NEXP, H2/64), 256, 0, stream>>>(x, w1, b1, idxw, act);
    expert_down<<<dim3(NEXP, DIM/64, 2), 256, 0, stream>>>(act, w2, b2, idxw, eww, out);
}

// Round 16
// 52.110 us; speedup vs baseline: 1.5084x; 1.5084x over previous
//
#include <hip/hip_runtime.h>

#define DIM 512
#define HIDDEN 1024
#define H2 2048        // 2*HIDDEN
#define NEXP 32
#define TOPK 4
#define TOKENS 64
#define NPAIR (TOKENS*TOPK)   // 256
#define PADK 8                // ushort pad per LDS row (16B-aligned rows, 2-way alias free)

typedef __attribute__((ext_vector_type(8))) short short8;
typedef __attribute__((ext_vector_type(4))) float fp32x4;

// f32 -> bf16 round-nearest-even
__device__ __forceinline__ unsigned short f2bf_rne(float f) {
    unsigned u = __float_as_uint(f);
    return (unsigned short)((u + 0x7FFFu + ((u >> 16) & 1u)) >> 16);
}
// f32 -> packed (hi | lo<<16): hi = truncate-to-bf16, lo = RNE(residual)
__device__ __forceinline__ unsigned split2p(float f) {
    unsigned u = __float_as_uint(f);
    unsigned short h = (unsigned short)(u >> 16);
    float hf = __uint_as_float(u & 0xFFFF0000u);
    unsigned short lo = f2bf_rne(f - hf);
    return (unsigned)h | ((unsigned)lo << 16);
}
__device__ __forceinline__ float dot4f(float4 a, float4 b) {
    return a.x*b.x + a.y*b.y + a.z*b.z + a.w*b.w;
}

// R12-frozen K-loop step: split ca,cb -> A-frags (hi,lo), 2 MFMAs vs LDS B-frag
#define MFMA_STEP(xbuf, ca, cb, kt) do {                                      \
    short8 ah, al; unsigned pk;                                               \
    pk = split2p((ca).x); ah[0]=(short)(pk & 0xFFFF); al[0]=(short)(pk >> 16);\
    pk = split2p((ca).y); ah[1]=(short)(pk & 0xFFFF); al[1]=(short)(pk >> 16);\
    pk = split2p((ca).z); ah[2]=(short)(pk & 0xFFFF); al[2]=(short)(pk >> 16);\
    pk = split2p((ca).w); ah[3]=(short)(pk & 0xFFFF); al[3]=(short)(pk >> 16);\
    pk = split2p((cb).x); ah[4]=(short)(pk & 0xFFFF); al[4]=(short)(pk >> 16);\
    pk = split2p((cb).y); ah[5]=(short)(pk & 0xFFFF); al[5]=(short)(pk >> 16);\
    pk = split2p((cb).z); ah[6]=(short)(pk & 0xFFFF); al[6]=(short)(pk >> 16);\
    pk = split2p((cb).w); ah[7]=(short)(pk & 0xFFFF); al[7]=(short)(pk >> 16);\
    short8 bh = *(const short8*)&xbuf[lr][(kt)*32 + lg*8];                    \
    acc = __builtin_amdgcn_mfma_f32_16x16x32_bf16(ah, bh, acc, 0, 0, 0);      \
    acc = __builtin_amdgcn_mfma_f32_16x16x32_bf16(al, bh, acc, 0, 0, 0);      \
} while (0)

// ---------------- router: 16-way split-K logits + top4 + softmax ----------
// 64 blocks x 512 thr. Also zeroes out[b][:] and writes x row as bf16.
__global__ __launch_bounds__(512) void router_kernel(
        const float* __restrict__ x, const float* __restrict__ Wg,
        const float* __restrict__ bg, int* __restrict__ idxw,
        float* __restrict__ eww, unsigned short* __restrict__ xb16,
        float* __restrict__ out) {
    int b = blockIdx.x;
    int tid = threadIdx.x;
    int e = tid >> 4, s = tid & 15;
    __shared__ float xs[DIM];
    __shared__ float g[NEXP];
    if (tid < DIM/4) {
        *(float4*)&xs[4*tid] = *(const float4*)(x + (size_t)b*DIM + 4*tid);
    }
    if (tid >= 128 && tid < 256) {
        int i = tid - 128;
        *(float4*)(out + (size_t)b*DIM + 4*i) = make_float4(0.f,0.f,0.f,0.f);
    }
    __syncthreads();
    xb16[(size_t)b*DIM + tid] = f2bf_rne(xs[tid]);   // tid < 512 = DIM
    const float* wr = Wg + e*DIM;
    float acc = 0.f;
    #pragma unroll
    for (int i = 0; i < 8; ++i) {
        int d4 = s + 16*i;
        float4 wv = *(const float4*)(wr + 4*d4);
        float4 xv = *(const float4*)&xs[4*d4];
        acc += dot4f(wv, xv);
    }
    #pragma unroll
    for (int m = 1; m < 16; m <<= 1) acc += __shfl_xor(acc, m);
    if (s == 0) g[e] = acc + bg[e];
    __syncthreads();
    if (tid == 0) {
        int sel[TOPK]; float val[TOPK];
        bool used[NEXP];
        for (int i = 0; i < NEXP; ++i) used[i] = false;
        for (int k = 0; k < TOPK; ++k) {
            float best = -1e30f; int bi = 0;
            for (int ee = 0; ee < NEXP; ++ee) {
                if (!used[ee] && g[ee] > best) { best = g[ee]; bi = ee; }
            }
            used[bi] = true; sel[k] = bi; val[k] = best;
        }
        float m = val[0];
        float p[TOPK]; float sum = 0.f;
        for (int k = 0; k < TOPK; ++k) { p[k] = __expf(val[k] - m); sum += p[k]; }
        float inv = 1.f / sum;
        for (int k = 0; k < TOPK; ++k) {
            idxw[b*TOPK + k] = sel[k];
            eww[b*TOPK + k]  = p[k] * inv;
        }
    }
}

// Ballot-based deterministic per-expert list build. Caller: 256 threads.
__device__ __forceinline__ int build_list_ballot(
        const int* __restrict__ idxw, int e, int tid,
        int* slist, unsigned long long* smask, int* scnt) {
    int me = idxw[tid];
    unsigned long long m = __ballot(me == e);
    int l = tid & 63, w = tid >> 6;
    if (l == 0) smask[w] = m;
    __syncthreads();
    if (me == e) {
        int r = __popcll(m & ((1ull << l) - 1ull));
        #pragma unroll
        for (int q = 0; q < 4; ++q) r += (q < w) ? __popcll(smask[q]) : 0;
        slist[r] = tid;
    }
    if (tid == 0) {
        *scnt = __popcll(smask[0]) + __popcll(smask[1])
              + __popcll(smask[2]) + __popcll(smask[3]);
    }
    __syncthreads();
    return *scnt;
}

// ---------------- expert up-proj + swiglu (MFMA, depth-2 branchless) ------
// block = 256 thr = 4 waves; wave owns 16 raw w1 rows x 16 tokens.
// grid (NEXP, H2/64 = 32). Staging = pure bf16 copy from xb16.
__global__ __launch_bounds__(256, 4) void expert_up(
        const unsigned short* __restrict__ xb16, const float* __restrict__ w1,
        const float* __restrict__ b1, const int* __restrict__ idxw,
        unsigned short* __restrict__ actb) {
    int e = blockIdx.x;
    int tid = threadIdx.x;
    __shared__ int slist[TOKENS];
    __shared__ unsigned long long smask[4];
    __shared__ int scnt;
    int n = build_list_ballot(idxw, e, tid, slist, smask, &scnt);
    if (n == 0) return;
    int wv = tid >> 6, l = tid & 63;
    int lr = l & 15, lg = l >> 4;          // A row-in-tile / k-group
    __shared__ unsigned short xh[16][DIM + PADK];   // 16.25 KB
    int r0 = blockIdx.y * 64 + wv * 16;    // raw row tile base (0..2047)
    const float4* w4 = (const float4*)(w1 + ((size_t)e*H2 + r0 + lr) * DIM + lg * 8);

    for (int t0 = 0; t0 < n; t0 += 16) {
        int nn = min(16, n - t0);
        __syncthreads();
        for (int i = tid; i < 16 * (DIM/8); i += 256) {  // 1024: short8 copies
            int j = i >> 6, dd = i & 63;
            short8 v = {0,0,0,0,0,0,0,0};
            if (j < nn) {
                int p = slist[t0 + j];
                v = *(const short8*)(xb16 + (size_t)(p >> 2)*DIM + 8*dd);
            }
            *(short8*)&xh[j][8*dd] = v;
        }
        __syncthreads();

        fp32x4 acc = {0.f, 0.f, 0.f, 0.f};
        float4 c0 = w4[0], c1 = w4[1];      // kt=0 in flight
        for (int kt = 0; kt < 16; ++kt) {
            int ktn = (kt + 1) & 15;        // branchless wrap (last reloads kt0)
            float4 n0 = w4[8*ktn], n1 = w4[8*ktn + 1];
            MFMA_STEP(xh, c0, c1, kt);
            c0 = n0; c1 = n1;
        }

        // D: col = l&15 = token, row = (l>>4)*4 + reg.
        int tok = lr;
        if (tok < nn) {
            int p = slist[t0 + tok];
            #pragma unroll
            for (int u = 0; u < 2; ++u) {
                int rr = r0 + lg*4 + 2*u;             // even raw row
                float h0 = acc[2*u]   + b1[e*H2 + rr];
                float h1 = acc[2*u+1] + b1[e*H2 + rr + 1];
                float gv = fminf(h0, 7.f);
                float lvv = fminf(fmaxf(h1, -7.f), 7.f);
                float sg = 1.f / (1.f + __expf(-1.702f * gv));
                // bf16 store == what expert_down's staging used to compute
                actb[(size_t)p*HIDDEN + (rr >> 1)] = f2bf_rne(gv * sg * (lvv + 1.f));
            }
        }
    }
}

// ---------------- expert down-proj + fused combine (k-split x2, atomic) ---
// block = 256 thr = 4 waves; wave owns 16 w2 rows x 16 tokens x K/2.
// grid (NEXP, DIM/64 = 8, 2). Staging = pure bf16 copy from actb.
__global__ __launch_bounds__(256, 4) void expert_down(
        const unsigned short* __restrict__ actb, const float* __restrict__ w2,
        const float* __restrict__ b2, const int* __restrict__ idxw,
        const float* __restrict__ eww, float* __restrict__ out) {
    int e = blockIdx.x;
    int kz = blockIdx.z;                   // K half: 0 or 1
    int tid = threadIdx.x;
    __shared__ int slist[TOKENS];
    __shared__ unsigned long long smask[4];
    __shared__ int scnt;
    int n = build_list_ballot(idxw, e, tid, slist, smask, &scnt);
    if (n == 0) return;
    int wv = tid >> 6, l = tid & 63;
    int lr = l & 15, lg = l >> 4;
    __shared__ unsigned short as_[16][HIDDEN/2 + PADK];  // 16.25 KB
    int r0 = blockIdx.y * 64 + wv * 16;    // output row tile base (0..511)
    const float4* w4 = (const float4*)(w2 + ((size_t)e*DIM + r0 + lr) * HIDDEN
                                       + kz * (HIDDEN/2) + lg * 8);

    for (int t0 = 0; t0 < n; t0 += 16) {
        int nn = min(16, n - t0);
        __syncthreads();
        for (int i = tid; i < 16 * (HIDDEN/16); i += 256) {  // 1024: short8 copies
            int j = i >> 6, dd = i & 63;
            short8 v = {0,0,0,0,0,0,0,0};
            if (j < nn) {
                int p = slist[t0 + j];
                v = *(const short8*)(actb + (size_t)p*HIDDEN + kz*(HIDDEN/2) + 8*dd);
            }
            *(short8*)&as_[j][8*dd] = v;
        }
        __syncthreads();

        fp32x4 acc = {0.f, 0.f, 0.f, 0.f};
        float4 c0 = w4[0], c1 = w4[1];
        for (int kt = 0; kt < 16; ++kt) {
            int ktn = (kt + 1) & 15;        // branchless wrap
            float4 n0 = w4[8*ktn], n1 = w4[8*ktn + 1];
            MFMA_STEP(as_, c0, c1, kt);
            c0 = n0; c1 = n1;
        }

        int tok = lr;
        if (tok < nn) {
            int p = slist[t0 + tok];
            float ew = eww[p];
            int b = p >> 2;
            #pragma unroll
            for (int u = 0; u < 4; ++u) {
                int rr = r0 + lg*4 + u;
                float v = acc[u] + (kz == 0 ? b2[e*DIM + rr] : 0.f);
                atomicAdd(out + (size_t)b*DIM + rr, ew * v);
            }
        }
    }
}

extern "C" void kernel_launch(void* const* d_in, const int* in_sizes, int n_in,
                              void* d_out, int out_size, void* d_ws, size_t ws_size,
                              hipStream_t stream) {
    const float* x  = (const float*)d_in[0];
    const float* Wg = (const float*)d_in[1];
    const float* bg = (const float*)d_in[2];
    const float* w1 = (const float*)d_in[3];
    const float* b1 = (const float*)d_in[4];
    const float* w2 = (const float*)d_in[5];
    const float* b2 = (const float*)d_in[6];
    float* out = (float*)d_out;

    char* ws = (char*)d_ws;
    int*            idxw = (int*)(ws);                   // 1 KB
    float*          eww  = (float*)(ws + 1024);          // 1 KB
    unsigned short* xb16 = (unsigned short*)(ws + 4096); // 64*512*2 = 64 KB
    unsigned short* actb = (unsigned short*)(ws + 81920);// 256*1024*2 = 512 KB

    router_kernel<<<TOKENS, 512, 0, stream>>>(x, Wg, bg, idxw, eww, xb16, out);
    expert_up<<<dim3(NEXP, H2/64), 256, 0, stream>>>(xb16, w1, b1, idxw, actb);
    expert_down<<<dim3(NEXP, DIM/64, 2), 256, 0, stream>>>(actb, w2, b2, idxw, eww, out);
}

// Round 18
// 51.589 us; speedup vs baseline: 1.5237x; 1.0101x over previous
//
#include <hip/hip_runtime.h>

#define DIM 512
#define HIDDEN 1024
#define H2 2048        // 2*HIDDEN
#define NEXP 32
#define TOPK 4
#define TOKENS 64
#define NPAIR (TOKENS*TOPK)   // 256
#define PADK 8                // ushort pad per LDS row (16B-aligned rows, 2-way alias free)

typedef __attribute__((ext_vector_type(8))) short short8;
typedef __attribute__((ext_vector_type(4))) float fp32x4;
typedef __attribute__((ext_vector_type(4))) unsigned uint4v;

// f32 -> bf16 round-nearest-even (bit trick)
__device__ __forceinline__ unsigned short f2bf_rne(float f) {
    unsigned u = __float_as_uint(f);
    return (unsigned short)((u + 0x7FFFu + ((u >> 16) & 1u)) >> 16);
}
// packed f32x2 -> bf16x2, pure integer ops (SSA-friendly, no unions/classes)
__device__ __forceinline__ unsigned pk_bf16(float a, float b) {
    return (unsigned)f2bf_rne(a) | ((unsigned)f2bf_rne(b) << 16);
}
__device__ __forceinline__ float dot4f(float4 a, float4 b) {
    return a.x*b.x + a.y*b.y + a.z*b.z + a.w*b.w;
}

// K-loop step: cvt ca,cb -> single bf16 A-frag, 1 MFMA vs LDS B-frag.
// (hi/lo split retired: bf16 weight rounding ~2^-9 rel, same order as the
// x/act bf16 rounding already in the error budget; halves MFMA + VALU.)
#define MFMA_STEP(xbuf, ca, cb, kt) do {                                      \
    uint4v au_;                                                               \
    au_[0] = pk_bf16((ca).x, (ca).y);                                         \
    au_[1] = pk_bf16((ca).z, (ca).w);                                         \
    au_[2] = pk_bf16((cb).x, (cb).y);                                         \
    au_[3] = pk_bf16((cb).z, (cb).w);                                         \
    short8 ah = __builtin_bit_cast(short8, au_);                              \
    short8 bh = *(const short8*)&xbuf[lr][(kt)*32 + lg*8];                    \
    acc = __builtin_amdgcn_mfma_f32_16x16x32_bf16(ah, bh, acc, 0, 0, 0);      \
} while (0)

// ---------------- router: 16-way split-K logits + top4 + softmax ----------
// 64 blocks x 512 thr. Also zeroes out[b][:] and writes x row as bf16.
__global__ __launch_bounds__(512) void router_kernel(
        const float* __restrict__ x, const float* __restrict__ Wg,
        const float* __restrict__ bg, int* __restrict__ idxw,
        float* __restrict__ eww, unsigned short* __restrict__ xb16,
        float* __restrict__ out) {
    int b = blockIdx.x;
    int tid = threadIdx.x;
    int e = tid >> 4, s = tid & 15;
    __shared__ float xs[DIM];
    __shared__ float g[NEXP];
    if (tid < DIM/4) {
        *(float4*)&xs[4*tid] = *(const float4*)(x + (size_t)b*DIM + 4*tid);
    }
    if (tid >= 128 && tid < 256) {
        int i = tid - 128;
        *(float4*)(out + (size_t)b*DIM + 4*i) = make_float4(0.f,0.f,0.f,0.f);
    }
    __syncthreads();
    xb16[(size_t)b*DIM + tid] = f2bf_rne(xs[tid]);   // tid < 512 = DIM
    const float* wr = Wg + e*DIM;
    float acc = 0.f;
    #pragma unroll
    for (int i = 0; i < 8; ++i) {
        int d4 = s + 16*i;
        float4 wv = *(const float4*)(wr + 4*d4);
        float4 xv = *(const float4*)&xs[4*d4];
        acc += dot4f(wv, xv);
    }
    #pragma unroll
    for (int m = 1; m < 16; m <<= 1) acc += __shfl_xor(acc, m);
    if (s == 0) g[e] = acc + bg[e];
    __syncthreads();
    if (tid == 0) {
        int sel[TOPK]; float val[TOPK];
        bool used[NEXP];
        for (int i = 0; i < NEXP; ++i) used[i] = false;
        for (int k = 0; k < TOPK; ++k) {
            float best = -1e30f; int bi = 0;
            for (int ee = 0; ee < NEXP; ++ee) {
                if (!used[ee] && g[ee] > best) { best = g[ee]; bi = ee; }
            }
            used[bi] = true; sel[k] = bi; val[k] = best;
        }
        float m = val[0];
        float p[TOPK]; float sum = 0.f;
        for (int k = 0; k < TOPK; ++k) { p[k] = __expf(val[k] - m); sum += p[k]; }
        float inv = 1.f / sum;
        for (int k = 0; k < TOPK; ++k) {
            idxw[b*TOPK + k] = sel[k];
            eww[b*TOPK + k]  = p[k] * inv;
        }
    }
}

// Ballot-based deterministic per-expert list build. Caller: 256 threads.
__device__ __forceinline__ int build_list_ballot(
        const int* __restrict__ idxw, int e, int tid,
        int* slist, unsigned long long* smask, int* scnt) {
    int me = idxw[tid];
    unsigned long long m = __ballot(me == e);
    int l = tid & 63, w = tid >> 6;
    if (l == 0) smask[w] = m;
    __syncthreads();
    if (me == e) {
        int r = __popcll(m & ((1ull << l) - 1ull));
        #pragma unroll
        for (int q = 0; q < 4; ++q) r += (q < w) ? __popcll(smask[q]) : 0;
        slist[r] = tid;
    }
    if (tid == 0) {
        *scnt = __popcll(smask[0]) + __popcll(smask[1])
              + __popcll(smask[2]) + __popcll(smask[3]);
    }
    __syncthreads();
    return *scnt;
}

// ---------------- expert up-proj + swiglu (MFMA, depth-2 branchless) ------
// block = 256 thr = 4 waves; wave owns 16 raw w1 rows x 16 tokens.
// grid (NEXP, H2/64 = 32). Staging = pure bf16 copy from xb16.
__global__ __launch_bounds__(256, 4) void expert_up(
        const unsigned short* __restrict__ xb16, const float* __restrict__ w1,
        const float* __restrict__ b1, const int* __restrict__ idxw,
        unsigned short* __restrict__ actb) {
    int e = blockIdx.x;
    int tid = threadIdx.x;
    __shared__ int slist[TOKENS];
    __shared__ unsigned long long smask[4];
    __shared__ int scnt;
    int n = build_list_ballot(idxw, e, tid, slist, smask, &scnt);
    if (n == 0) return;
    int wv = tid >> 6, l = tid & 63;
    int lr = l & 15, lg = l >> 4;          // A row-in-tile / k-group
    __shared__ unsigned short xh[16][DIM + PADK];   // 16.25 KB
    int r0 = blockIdx.y * 64 + wv * 16;    // raw row tile base (0..2047)
    const float4* w4 = (const float4*)(w1 + ((size_t)e*H2 + r0 + lr) * DIM + lg * 8);

    for (int t0 = 0; t0 < n; t0 += 16) {
        int nn = min(16, n - t0);
        __syncthreads();
        for (int i = tid; i < 16 * (DIM/8); i += 256) {  // 1024: short8 copies
            int j = i >> 6, dd = i & 63;
            short8 v = {0,0,0,0,0,0,0,0};
            if (j < nn) {
                int p = slist[t0 + j];
                v = *(const short8*)(xb16 + (size_t)(p >> 2)*DIM + 8*dd);
            }
            *(short8*)&xh[j][8*dd] = v;
        }
        __syncthreads();

        fp32x4 acc = {0.f, 0.f, 0.f, 0.f};
        float4 c0 = w4[0], c1 = w4[1];      // kt=0 in flight
        for (int kt = 0; kt < 16; ++kt) {
            int ktn = (kt + 1) & 15;        // branchless wrap (last reloads kt0)
            float4 n0 = w4[8*ktn], n1 = w4[8*ktn + 1];
            MFMA_STEP(xh, c0, c1, kt);
            c0 = n0; c1 = n1;
        }

        // D: col = l&15 = token, row = (l>>4)*4 + reg.
        int tok = lr;
        if (tok < nn) {
            int p = slist[t0 + tok];
            #pragma unroll
            for (int u = 0; u < 2; ++u) {
                int rr = r0 + lg*4 + 2*u;             // even raw row
                float h0 = acc[2*u]   + b1[e*H2 + rr];
                float h1 = acc[2*u+1] + b1[e*H2 + rr + 1];
                float gv = fminf(h0, 7.f);
                float lvv = fminf(fmaxf(h1, -7.f), 7.f);
                float sg = 1.f / (1.f + __expf(-1.702f * gv));
                actb[(size_t)p*HIDDEN + (rr >> 1)] = f2bf_rne(gv * sg * (lvv + 1.f));
            }
        }
    }
}

// ---------------- expert down-proj + fused combine (k-split x2, atomic) ---
// block = 256 thr = 4 waves; wave owns 16 w2 rows x 16 tokens x K/2.
// grid (NEXP, DIM/64 = 8, 2). Staging = pure bf16 copy from actb.
__global__ __launch_bounds__(256, 4) void expert_down(
        const unsigned short* __restrict__ actb, const float* __restrict__ w2,
        const float* __restrict__ b2, const int* __restrict__ idxw,
        const float* __restrict__ eww, float* __restrict__ out) {
    int e = blockIdx.x;
    int kz = blockIdx.z;                   // K half: 0 or 1
    int tid = threadIdx.x;
    __shared__ int slist[TOKENS];
    __shared__ unsigned long long smask[4];
    __shared__ int scnt;
    int n = build_list_ballot(idxw, e, tid, slist, smask, &scnt);
    if (n == 0) return;
    int wv = tid >> 6, l = tid & 63;
    int lr = l & 15, lg = l >> 4;
    __shared__ unsigned short as_[16][HIDDEN/2 + PADK];  // 16.25 KB
    int r0 = blockIdx.y * 64 + wv * 16;    // output row tile base (0..511)
    const float4* w4 = (const float4*)(w2 + ((size_t)e*DIM + r0 + lr) * HIDDEN
                                       + kz * (HIDDEN/2) + lg * 8);

    for (int t0 = 0; t0 < n; t0 += 16) {
        int nn = min(16, n - t0);
        __syncthreads();
        for (int i = tid; i < 16 * (HIDDEN/16); i += 256) {  // 1024: short8 copies
            int j = i >> 6, dd = i & 63;
            short8 v = {0,0,0,0,0,0,0,0};
            if (j < nn) {
                int p = slist[t0 + j];
                v = *(const short8*)(actb + (size_t)p*HIDDEN + kz*(HIDDEN/2) + 8*dd);
            }
            *(short8*)&as_[j][8*dd] = v;
        }
        __syncthreads();

        fp32x4 acc = {0.f, 0.f, 0.f, 0.f};
        float4 c0 = w4[0], c1 = w4[1];
        for (int kt = 0; kt < 16; ++kt) {
            int ktn = (kt + 1) & 15;        // branchless wrap
            float4 n0 = w4[8*ktn], n1 = w4[8*ktn + 1];
            MFMA_STEP(as_, c0, c1, kt);
            c0 = n0; c1 = n1;
        }

        int tok = lr;
        if (tok < nn) {
            int p = slist[t0 + tok];
            float ew = eww[p];
            int b = p >> 2;
            #pragma unroll
            for (int u = 0; u < 4; ++u) {
                int rr = r0 + lg*4 + u;
                float v = acc[u] + (kz == 0 ? b2[e*DIM + rr] : 0.f);
                atomicAdd(out + (size_t)b*DIM + rr, ew * v);
            }
        }
    }
}

extern "C" void kernel_launch(void* const* d_in, const int* in_sizes, int n_in,
                              void* d_out, int out_size, void* d_ws, size_t ws_size,
                              hipStream_t stream) {
    const float* x  = (const float*)d_in[0];
    const float* Wg = (const float*)d_in[1];
    const float* bg = (const float*)d_in[2];
    const float* w1 = (const float*)d_in[3];
    const float* b1 = (const float*)d_in[4];
    const float* w2 = (const float*)d_in[5];
    const float* b2 = (const float*)d_in[6];
    float* out = (float*)d_out;

    char* ws = (char*)d_ws;
    int*            idxw = (int*)(ws);                   // 1 KB
    float*          eww  = (float*)(ws + 1024);          // 1 KB
    unsigned short* xb16 = (unsigned short*)(ws + 4096); // 64*512*2 = 64 KB
    unsigned short* actb = (unsigned short*)(ws + 81920);// 256*1024*2 = 512 KB

    router_kernel<<<TOKENS, 512, 0, stream>>>(x, Wg, bg, idxw, eww, xb16, out);
    expert_up<<<dim3(NEXP, H2/64), 256, 0, stream>>>(xb16, w1, b1, idxw, actb);
    expert_down<<<dim3(NEXP, DIM/64, 2), 256, 0, stream>>>(actb, w2, b2, idxw, eww, out);
}

// Round 19
// 51.395 us; speedup vs baseline: 1.5294x; 1.0038x over previous
//
#include <hip/hip_runtime.h>

#define DIM 512
#define HIDDEN 1024
#define H2 2048        // 2*HIDDEN
#define NEXP 32
#define TOPK 4
#define TOKENS 64
#define NPAIR (TOKENS*TOPK)   // 256
#define PADK 8                // ushort pad per LDS row (16B-aligned rows, 2-way alias free)

typedef __attribute__((ext_vector_type(8))) short short8;
typedef __attribute__((ext_vector_type(4))) float fp32x4;
typedef __attribute__((ext_vector_type(4))) unsigned uint4v;

// f32 -> bf16 round-nearest-even (bit trick)
__device__ __forceinline__ unsigned short f2bf_rne(float f) {
    unsigned u = __float_as_uint(f);
    return (unsigned short)((u + 0x7FFFu + ((u >> 16) & 1u)) >> 16);
}
// packed f32x2 -> bf16x2, pure integer ops (SSA-friendly, no unions/classes)
__device__ __forceinline__ unsigned pk_bf16(float a, float b) {
    return (unsigned)f2bf_rne(a) | ((unsigned)f2bf_rne(b) << 16);
}
__device__ __forceinline__ float dot4f(float4 a, float4 b) {
    return a.x*b.x + a.y*b.y + a.z*b.z + a.w*b.w;
}

// K-loop step: cvt ca,cb -> single bf16 A-frag, 1 MFMA vs LDS B-frag.
#define MFMA_STEP(xbuf, ca, cb, kt) do {                                      \
    uint4v au_;                                                               \
    au_[0] = pk_bf16((ca).x, (ca).y);                                         \
    au_[1] = pk_bf16((ca).z, (ca).w);                                         \
    au_[2] = pk_bf16((cb).x, (cb).y);                                         \
    au_[3] = pk_bf16((cb).z, (cb).w);                                         \
    short8 ah = __builtin_bit_cast(short8, au_);                              \
    short8 bh = *(const short8*)&xbuf[lr][(kt)*32 + lg*8];                    \
    acc = __builtin_amdgcn_mfma_f32_16x16x32_bf16(ah, bh, acc, 0, 0, 0);      \
} while (0)

// Depth-4 branchless ring over 16 kts: 8 loads grouped at top of each
// 4-kt group (static names, no runtime-indexed arrays, no guards).
#define KLOOP16_D4(xbuf, w4) do {                                             \
    float4 pa0 = (w4)[0],  pb0 = (w4)[1];                                     \
    float4 pa1 = (w4)[8],  pb1 = (w4)[9];                                     \
    float4 pa2 = (w4)[16], pb2 = (w4)[17];                                    \
    float4 pa3 = (w4)[24], pb3 = (w4)[25];                                    \
    for (int ktb = 0; ktb < 16; ktb += 4) {                                   \
        int k4 = (ktb+4)&15, k5 = (ktb+5)&15, k6 = (ktb+6)&15, k7 = (ktb+7)&15;\
        float4 na0 = (w4)[8*k4], nb0 = (w4)[8*k4+1];                          \
        float4 na1 = (w4)[8*k5], nb1 = (w4)[8*k5+1];                          \
        float4 na2 = (w4)[8*k6], nb2 = (w4)[8*k6+1];                          \
        float4 na3 = (w4)[8*k7], nb3 = (w4)[8*k7+1];                          \
        MFMA_STEP(xbuf, pa0, pb0, ktb);                                       \
        MFMA_STEP(xbuf, pa1, pb1, ktb+1);                                     \
        MFMA_STEP(xbuf, pa2, pb2, ktb+2);                                     \
        MFMA_STEP(xbuf, pa3, pb3, ktb+3);                                     \
        pa0 = na0; pb0 = nb0; pa1 = na1; pb1 = nb1;                           \
        pa2 = na2; pb2 = nb2; pa3 = na3; pb3 = nb3;                           \
    }                                                                         \
} while (0)

// ---------------- router: 16-way split-K logits + top4 + softmax ----------
// 64 blocks x 512 thr. Also zeroes out[b][:] and writes x row as bf16.
__global__ __launch_bounds__(512) void router_kernel(
        const float* __restrict__ x, const float* __restrict__ Wg,
        const float* __restrict__ bg, int* __restrict__ idxw,
        float* __restrict__ eww, unsigned short* __restrict__ xb16,
        float* __restrict__ out) {
    int b = blockIdx.x;
    int tid = threadIdx.x;
    int e = tid >> 4, s = tid & 15;
    __shared__ float xs[DIM];
    __shared__ float g[NEXP];
    if (tid < DIM/4) {
        *(float4*)&xs[4*tid] = *(const float4*)(x + (size_t)b*DIM + 4*tid);
    }
    if (tid >= 128 && tid < 256) {
        int i = tid - 128;
        *(float4*)(out + (size_t)b*DIM + 4*i) = make_float4(0.f,0.f,0.f,0.f);
    }
    __syncthreads();
    xb16[(size_t)b*DIM + tid] = f2bf_rne(xs[tid]);   // tid < 512 = DIM
    const float* wr = Wg + e*DIM;
    float acc = 0.f;
    #pragma unroll
    for (int i = 0; i < 8; ++i) {
        int d4 = s + 16*i;
        float4 wv = *(const float4*)(wr + 4*d4);
        float4 xv = *(const float4*)&xs[4*d4];
        acc += dot4f(wv, xv);
    }
    #pragma unroll
    for (int m = 1; m < 16; m <<= 1) acc += __shfl_xor(acc, m);
    if (s == 0) g[e] = acc + bg[e];
    __syncthreads();
    if (tid == 0) {
        int sel[TOPK]; float val[TOPK];
        bool used[NEXP];
        for (int i = 0; i < NEXP; ++i) used[i] = false;
        for (int k = 0; k < TOPK; ++k) {
            float best = -1e30f; int bi = 0;
            for (int ee = 0; ee < NEXP; ++ee) {
                if (!used[ee] && g[ee] > best) { best = g[ee]; bi = ee; }
            }
            used[bi] = true; sel[k] = bi; val[k] = best;
        }
        float m = val[0];
        float p[TOPK]; float sum = 0.f;
        for (int k = 0; k < TOPK; ++k) { p[k] = __expf(val[k] - m); sum += p[k]; }
        float inv = 1.f / sum;
        for (int k = 0; k < TOPK; ++k) {
            idxw[b*TOPK + k] = sel[k];
            eww[b*TOPK + k]  = p[k] * inv;
        }
    }
}

// Ballot-based deterministic per-expert list build. Caller: 256 threads.
__device__ __forceinline__ int build_list_ballot(
        const int* __restrict__ idxw, int e, int tid,
        int* slist, unsigned long long* smask, int* scnt) {
    int me = idxw[tid];
    unsigned long long m = __ballot(me == e);
    int l = tid & 63, w = tid >> 6;
    if (l == 0) smask[w] = m;
    __syncthreads();
    if (me == e) {
        int r = __popcll(m & ((1ull << l) - 1ull));
        #pragma unroll
        for (int q = 0; q < 4; ++q) r += (q < w) ? __popcll(smask[q]) : 0;
        slist[r] = tid;
    }
    if (tid == 0) {
        *scnt = __popcll(smask[0]) + __popcll(smask[1])
              + __popcll(smask[2]) + __popcll(smask[3]);
    }
    __syncthreads();
    return *scnt;
}

// ---------------- expert up-proj + swiglu (MFMA, depth-4 ring) ------------
// block = 256 thr = 4 waves; wave owns 16 raw w1 rows x 16 tokens.
// grid (NEXP, H2/64 = 32). Staging = pure bf16 copy from xb16.
__global__ __launch_bounds__(256, 4) void expert_up(
        const unsigned short* __restrict__ xb16, const float* __restrict__ w1,
        const float* __restrict__ b1, const int* __restrict__ idxw,
        unsigned short* __restrict__ actb) {
    int e = blockIdx.x;
    int tid = threadIdx.x;
    __shared__ int slist[TOKENS];
    __shared__ unsigned long long smask[4];
    __shared__ int scnt;
    int n = build_list_ballot(idxw, e, tid, slist, smask, &scnt);
    if (n == 0) return;
    int wv = tid >> 6, l = tid & 63;
    int lr = l & 15, lg = l >> 4;          // A row-in-tile / k-group
    __shared__ unsigned short xh[16][DIM + PADK];   // 16.25 KB
    int r0 = blockIdx.y * 64 + wv * 16;    // raw row tile base (0..2047)
    const float4* w4 = (const float4*)(w1 + ((size_t)e*H2 + r0 + lr) * DIM + lg * 8);

    for (int t0 = 0; t0 < n; t0 += 16) {
        int nn = min(16, n - t0);
        __syncthreads();
        for (int i = tid; i < 16 * (DIM/8); i += 256) {  // 1024: short8 copies
            int j = i >> 6, dd = i & 63;
            short8 v = {0,0,0,0,0,0,0,0};
            if (j < nn) {
                int p = slist[t0 + j];
                v = *(const short8*)(xb16 + (size_t)(p >> 2)*DIM + 8*dd);
            }
            *(short8*)&xh[j][8*dd] = v;
        }
        __syncthreads();

        fp32x4 acc = {0.f, 0.f, 0.f, 0.f};
        KLOOP16_D4(xh, w4);

        // D: col = l&15 = token, row = (l>>4)*4 + reg.
        int tok = lr;
        if (tok < nn) {
            int p = slist[t0 + tok];
            #pragma unroll
            for (int u = 0; u < 2; ++u) {
                int rr = r0 + lg*4 + 2*u;             // even raw row
                float h0 = acc[2*u]   + b1[e*H2 + rr];
                float h1 = acc[2*u+1] + b1[e*H2 + rr + 1];
                float gv = fminf(h0, 7.f);
                float lvv = fminf(fmaxf(h1, -7.f), 7.f);
                float sg = 1.f / (1.f + __expf(-1.702f * gv));
                actb[(size_t)p*HIDDEN + (rr >> 1)] = f2bf_rne(gv * sg * (lvv + 1.f));
            }
        }
    }
}

// ---------------- expert down-proj + fused combine (k-split x2, atomic) ---
// block = 256 thr = 4 waves; wave owns 16 w2 rows x 16 tokens x K/2.
// grid (NEXP, DIM/64 = 8, 2). Staging = pure bf16 copy from actb.
__global__ __launch_bounds__(256, 4) void expert_down(
        const unsigned short* __restrict__ actb, const float* __restrict__ w2,
        const float* __restrict__ b2, const int* __restrict__ idxw,
        const float* __restrict__ eww, float* __restrict__ out) {
    int e = blockIdx.x;
    int kz = blockIdx.z;                   // K half: 0 or 1
    int tid = threadIdx.x;
    __shared__ int slist[TOKENS];
    __shared__ unsigned long long smask[4];
    __shared__ int scnt;
    int n = build_list_ballot(idxw, e, tid, slist, smask, &scnt);
    if (n == 0) return;
    int wv = tid >> 6, l = tid & 63;
    int lr = l & 15, lg = l >> 4;
    __shared__ unsigned short as_[16][HIDDEN/2 + PADK];  // 16.25 KB
    int r0 = blockIdx.y * 64 + wv * 16;    // output row tile base (0..511)
    const float4* w4 = (const float4*)(w2 + ((size_t)e*DIM + r0 + lr) * HIDDEN
                                       + kz * (HIDDEN/2) + lg * 8);

    for (int t0 = 0; t0 < n; t0 += 16) {
        int nn = min(16, n - t0);
        __syncthreads();
        for (int i = tid; i < 16 * (HIDDEN/16); i += 256) {  // 1024: short8 copies
            int j = i >> 6, dd = i & 63;
            short8 v = {0,0,0,0,0,0,0,0};
            if (j < nn) {
                int p = slist[t0 + j];
                v = *(const short8*)(actb + (size_t)p*HIDDEN + kz*(HIDDEN/2) + 8*dd);
            }
            *(short8*)&as_[j][8*dd] = v;
        }
        __syncthreads();

        fp32x4 acc = {0.f, 0.f, 0.f, 0.f};
        KLOOP16_D4(as_, w4);

        int tok = lr;
        if (tok < nn) {
            int p = slist[t0 + tok];
            float ew = eww[p];
            int b = p >> 2;
            #pragma unroll
            for (int u = 0; u < 4; ++u) {
                int rr = r0 + lg*4 + u;
                float v = acc[u] + (kz == 0 ? b2[e*DIM + rr] : 0.f);
                atomicAdd(out + (size_t)b*DIM + rr, ew * v);
            }
        }
    }
}

extern "C" void kernel_launch(void* const* d_in, const int* in_sizes, int n_in,
                              void* d_out, int out_size, void* d_ws, size_t ws_size,
                              hipStream_t stream) {
    const float* x  = (const float*)d_in[0];
    const float* Wg = (const float*)d_in[1];
    const float* bg = (const float*)d_in[2];
    const float* w1 = (const float*)d_in[3];
    const float* b1 = (const float*)d_in[4];
    const float* w2 = (const float*)d_in[5];
    const float* b2 = (const float*)d_in[6];
    float* out = (float*)d_out;

    char* ws = (char*)d_ws;
    int*            idxw = (int*)(ws);                   // 1 KB
    float*          eww  = (float*)(ws + 1024);          // 1 KB
    unsigned short* xb16 = (unsigned short*)(ws + 4096); // 64*512*2 = 64 KB
    unsigned short* actb = (unsigned short*)(ws + 81920);// 256*1024*2 = 512 KB

    router_kernel<<<TOKENS, 512, 0, stream>>>(x, Wg, bg, idxw, eww, xb16, out);
    expert_up<<<dim3(NEXP, H2/64), 256, 0, stream>>>(xb16, w1, b1, idxw, actb);
    expert_down<<<dim3(NEXP, DIM/64, 2), 256, 0, stream>>>(actb, w2, b2, idxw, eww, out);
}